// Round 1
// baseline (9.734 us; speedup 1.0000x reference)
//
#include <hip/hip_runtime.h>
#include <math.h>

#define N_QUBITS 8

// Closed form: the circuit (RY-encode -> RX layer -> CNOT ring -> <Z_i>)
// reduces per sample to z_i = cos(w_i)*cos(theta_i) with
//   out[0] = z1*z2*...*z7,  out[k] = z0*z1*...*zk  (k>=1)
// where theta_i = (x_i - mean)/(std_ddof1 + 1e-6) * pi.
__global__ __launch_bounds__(256) void QuantumLayer_kernel(
    const float* __restrict__ x,      // (B, 8)
    const float* __restrict__ w,      // (1, 8)
    float* __restrict__ out,          // (B, 8)
    int B)
{
    int b = blockIdx.x * blockDim.x + threadIdx.x;
    if (b >= B) return;

    // Vectorized coalesced load of this sample's 8 floats (32 B/lane).
    const float4* xp = reinterpret_cast<const float4*>(x + (size_t)b * 8);
    float4 v0 = xp[0];
    float4 v1 = xp[1];
    float xv[8] = {v0.x, v0.y, v0.z, v0.w, v1.x, v1.y, v1.z, v1.w};

    // Per-sample standardization (ddof=1), matching jnp.std(..., ddof=1).
    float mean = 0.f;
    #pragma unroll
    for (int i = 0; i < 8; ++i) mean += xv[i];
    mean *= 0.125f;

    float var = 0.f;
    #pragma unroll
    for (int i = 0; i < 8; ++i) { float d = xv[i] - mean; var += d * d; }
    float stdv = sqrtf(var * (1.0f / 7.0f));
    float scale = 3.14159265358979323846f / (stdv + 1e-6f);

    // z_i = cos(w_i) * cos(theta_i)
    float z[8];
    #pragma unroll
    for (int i = 0; i < 8; ++i) {
        float theta = (xv[i] - mean) * scale;
        z[i] = cosf(w[i]) * cosf(theta);
    }

    // out[0] = prod_{i=1..7} z_i ; out[k] = prod_{i=0..k} z_i for k>=1
    float o[8];
    float suf = z[1];
    #pragma unroll
    for (int i = 2; i < 8; ++i) suf *= z[i];
    o[0] = suf;

    float run = z[0];
    #pragma unroll
    for (int i = 1; i < 8; ++i) { run *= z[i]; o[i] = run; }

    float4* op = reinterpret_cast<float4*>(out + (size_t)b * 8);
    op[0] = make_float4(o[0], o[1], o[2], o[3]);
    op[1] = make_float4(o[4], o[5], o[6], o[7]);
}

extern "C" void kernel_launch(void* const* d_in, const int* in_sizes, int n_in,
                              void* d_out, int out_size, void* d_ws, size_t ws_size,
                              hipStream_t stream) {
    const float* x = (const float*)d_in[0];
    const float* w = (const float*)d_in[1];
    float* out = (float*)d_out;

    int B = in_sizes[0] / N_QUBITS;  // 65536
    int block = 256;
    int grid = (B + block - 1) / block;
    QuantumLayer_kernel<<<grid, block, 0, stream>>>(x, w, out, B);
}